// Round 8
// baseline (43.888 us; speedup 1.0000x reference)
//
#include <hip/hip_runtime.h>
#include <hip/hip_bf16.h>

constexpr int B = 4;
constexpr int N = 50000;
constexpr int K = 128;
constexpr int S = 256;
constexpr int NCH = (N + 255) / 256;     // 196 chunks for error kernel (784 = 98*8 blocks)
constexpr float EPS = 1e-5f;

__device__ __forceinline__ float frcp  (float x) { return __builtin_amdgcn_rcpf(x); }
__device__ __forceinline__ float frsq  (float x) { return __builtin_amdgcn_rsqf(x); }
__device__ __forceinline__ float fsqrt_(float x) { return __builtin_amdgcn_sqrtf(x); }

// ---------------------------------------------------------------------------
// Static-indexed Jacobi solve (registers only — rule #20)
// ---------------------------------------------------------------------------
template<int P, int Q>
__device__ __forceinline__ void rot(float (&A)[4][4], float (&V)[4][4])
{
  const float apq = A[P][Q];
  const float theta = 0.5f * (A[Q][Q] - A[P][P]) * frcp(apq);
  const float tt = copysignf(
      frcp(fabsf(theta) + fsqrt_(fmaf(theta, theta, 1.f))), theta);
  float c  = frsq(fmaf(tt, tt, 1.f));
  float sn = tt * c;
  const bool tiny = fabsf(apq) < 1e-20f;
  c  = tiny ? 1.f : c;
  sn = tiny ? 0.f : sn;
  #pragma unroll
  for (int i = 0; i < 4; ++i) {
    const float aip = A[i][P], aiq = A[i][Q];
    A[i][P] = c * aip - sn * aiq;
    A[i][Q] = sn * aip + c * aiq;
  }
  #pragma unroll
  for (int i = 0; i < 4; ++i) {
    const float api = A[P][i], aqi = A[Q][i];
    A[P][i] = c * api - sn * aqi;
    A[Q][i] = sn * api + c * aqi;
  }
  #pragma unroll
  for (int i = 0; i < 4; ++i) {
    const float vip = V[i][P], viq = V[i][Q];
    V[i][P] = c * vip - sn * viq;
    V[i][Q] = sn * vip + c * viq;
  }
}

// Sm = {W, Σwp(3), Σwq(3), Σw p⊗q(9)}  ->  write 4x4 transform at To
__device__ __forceinline__ void solve_and_write(const float (&Sm)[16], float* To)
{
  const float W   = Sm[0];
  const float inv = frcp(W + EPS);
  const float scx = Sm[1]*inv, scy = Sm[2]*inv, scz = Sm[3]*inv;
  const float tcx = Sm[4]*inv, tcy = Sm[5]*inv, tcz = Sm[6]*inv;
  const float f = 2.f - W * inv;     // H = Σ(w s⊗t)·inv − (2−σ)·sc⊗tc
  const float Sxx = Sm[7]*inv  - f*scx*tcx;
  const float Sxy = Sm[8]*inv  - f*scx*tcy;
  const float Sxz = Sm[9]*inv  - f*scx*tcz;
  const float Syx = Sm[10]*inv - f*scy*tcx;
  const float Syy = Sm[11]*inv - f*scy*tcy;
  const float Syz = Sm[12]*inv - f*scy*tcz;
  const float Szx = Sm[13]*inv - f*scz*tcx;
  const float Szy = Sm[14]*inv - f*scz*tcy;
  const float Szz = Sm[15]*inv - f*scz*tcz;

  float A[4][4], V[4][4];
  A[0][0] = Sxx + Syy + Szz;
  A[0][1] = Syz - Szy;  A[0][2] = Szx - Sxz;  A[0][3] = Sxy - Syx;
  A[1][1] = Sxx - Syy - Szz;
  A[1][2] = Sxy + Syx;  A[1][3] = Szx + Sxz;
  A[2][2] = -Sxx + Syy - Szz;
  A[2][3] = Syz + Szy;
  A[3][3] = -Sxx - Syy + Szz;
  A[1][0] = A[0][1]; A[2][0] = A[0][2]; A[3][0] = A[0][3];
  A[2][1] = A[1][2]; A[3][1] = A[1][3]; A[3][2] = A[2][3];

  #pragma unroll
  for (int i = 0; i < 4; ++i)
    #pragma unroll
    for (int j = 0; j < 4; ++j) V[i][j] = (i == j) ? 1.f : 0.f;

  #pragma unroll 1
  for (int sweep = 0; sweep < 5; ++sweep) {
    rot<0,1>(A, V); rot<0,2>(A, V); rot<0,3>(A, V);
    rot<1,2>(A, V); rot<1,3>(A, V); rot<2,3>(A, V);
  }

  const float d0 = A[0][0], d1 = A[1][1], d2 = A[2][2], d3 = A[3][3];
  const bool b1 = d1 > d0;
  const bool b3 = d3 > d2;
  const bool bb = (b3 ? d3 : d2) > (b1 ? d1 : d0);
  float qw  = bb ? (b3 ? V[0][3] : V[0][2]) : (b1 ? V[0][1] : V[0][0]);
  float qxv = bb ? (b3 ? V[1][3] : V[1][2]) : (b1 ? V[1][1] : V[1][0]);
  float qyv = bb ? (b3 ? V[2][3] : V[2][2]) : (b1 ? V[2][1] : V[2][0]);
  float qzv = bb ? (b3 ? V[3][3] : V[3][2]) : (b1 ? V[3][1] : V[3][0]);

  const float qn = frsq(qw*qw + qxv*qxv + qyv*qyv + qzv*qzv);
  qw *= qn; qxv *= qn; qyv *= qn; qzv *= qn;

  const float R00 = 1.f - 2.f*(qyv*qyv + qzv*qzv);
  const float R01 = 2.f*(qxv*qyv - qw*qzv);
  const float R02 = 2.f*(qxv*qzv + qw*qyv);
  const float R10 = 2.f*(qxv*qyv + qw*qzv);
  const float R11 = 1.f - 2.f*(qxv*qxv + qzv*qzv);
  const float R12 = 2.f*(qyv*qzv - qw*qxv);
  const float R20 = 2.f*(qxv*qzv - qw*qyv);
  const float R21 = 2.f*(qyv*qzv + qw*qxv);
  const float R22 = 1.f - 2.f*(qxv*qxv + qyv*qyv);

  const float tx = tcx - (R00*scx + R01*scy + R02*scz);
  const float ty = tcy - (R10*scx + R11*scy + R12*scz);
  const float tz = tcz - (R20*scx + R21*scy + R22*scz);

  float4* T4 = (float4*)To;
  T4[0] = make_float4(R00, R01, R02, tx);
  T4[1] = make_float4(R10, R11, R12, ty);
  T4[2] = make_float4(R20, R21, R22, tz);
  T4[3] = make_float4(0.f, 0.f, 0.f, 1.f);
}

// ---------------------------------------------------------------------------
// Kernel 1: fused fit kernel (unchanged from R7). Block = (b,k), XCD-pinned:
// batch b's 1.4MB working set lives in XCD 2b/2b+1's L2.
// ---------------------------------------------------------------------------
__global__ __launch_bounds__(256) void gather_solve_kernel(
    const float* __restrict__ src, const float* __restrict__ tgt,
    const float* __restrict__ wts, const int* __restrict__ sel,
    float* __restrict__ T)
{
  const int bid = blockIdx.x;
  const int xcd = bid & 7;
  const int b   = xcd >> 1;                       // batch pinned to XCD pair
  const int k   = ((bid >> 3) << 1) | (xcd & 1);  // bijective over [0,128)
  const int s   = threadIdx.x;

  const int idx = sel[k * S + s];
  const float* ps = src + (size_t)(b * N + idx) * 3;
  const float* pt = tgt + (size_t)(b * N + idx) * 3;
  const float w  = wts[b * N + idx];
  const float px = ps[0], py = ps[1], pz = ps[2];
  const float qx = pt[0], qy = pt[1], qz = pt[2];

  float acc[16];
  acc[0] = w;
  acc[1] = w * px;  acc[2] = w * py;  acc[3] = w * pz;
  acc[4] = w * qx;  acc[5] = w * qy;  acc[6] = w * qz;
  acc[7]  = w * px * qx; acc[8]  = w * px * qy; acc[9]  = w * px * qz;
  acc[10] = w * py * qx; acc[11] = w * py * qy; acc[12] = w * py * qz;
  acc[13] = w * pz * qx; acc[14] = w * pz * qy; acc[15] = w * pz * qz;

  #pragma unroll
  for (int off = 32; off > 0; off >>= 1) {
    #pragma unroll
    for (int i = 0; i < 16; ++i)
      acc[i] += __shfl_down(acc[i], off);
  }

  __shared__ float red[4][16];
  const int lane = threadIdx.x & 63, wv = threadIdx.x >> 6;
  if (lane == 0) {
    #pragma unroll
    for (int i = 0; i < 16; ++i) red[wv][i] = acc[i];
  }
  __syncthreads();

  if (threadIdx.x == 0) {
    float Sm[16];
    #pragma unroll
    for (int i = 0; i < 16; ++i)
      Sm[i] = red[0][i] + red[1][i] + red[2][i] + red[3][i];
    solve_and_write(Sm, T + (size_t)(b * K + k) * 16);   // register-only solve
  }
}

// ---------------------------------------------------------------------------
// Kernel 2: error evaluation — SINGLE CHANGE THIS ROUND: XCD-pinned block
// mapping (784 = 98*8 blocks; bid&7 -> XCD; batch = xcd>>1). Previously
// b = blk/NCH round-robined every batch across every XCD, streaming 5.6MB
// through each 4MB XCD L2 per replay and EVICTING the gather kernel's warm
// set -> the fit gather ran cache-cold (L3 latency through limited per-CU
// miss queue) on every replay = the stable ~31µs fit cost. Now each XCD's
// L2 only holds its own batch's 1.4MB: gather + error stay L2-resident.
// ---------------------------------------------------------------------------
constexpr int KPT = 4;
constexpr int KG  = K / KPT;      // 32
constexpr int NSL = 256 / KG;     // 8
constexpr int PPS = 256 / NSL;    // 32

__global__ __launch_bounds__(256) void error_kernel(
    const float* __restrict__ src, const float* __restrict__ tgt,
    const float* __restrict__ wts, const float* __restrict__ T,
    float* __restrict__ partial)
{
  __shared__ float4 sp[256];
  __shared__ float4 sq[256];
  __shared__ float  t4[K][12];
  __shared__ float  red[K][NSL + 1];

  const int bid = blockIdx.x;
  const int xcd = bid & 7;
  const int b   = xcd >> 1;                        // batch pinned to XCD pair
  const int ch  = ((bid >> 3) << 1) | (xcd & 1);   // bijective over [0,196)
  const int tid = threadIdx.x;
  const int j   = ch * 256 + tid;

  float4 P = make_float4(0.f, 0.f, 0.f, 0.f);
  float4 Q = make_float4(0.f, 0.f, 0.f, 0.f);
  if (j < N) {
    const float* ps = src + (size_t)(b*N + j) * 3;
    const float* pt = tgt + (size_t)(b*N + j) * 3;
    P.x = ps[0]; P.y = ps[1]; P.z = ps[2]; P.w = wts[b*N + j];
    Q.x = pt[0]; Q.y = pt[1]; Q.z = pt[2];
  }
  sp[tid] = P; sq[tid] = Q;

  if (tid < K) {
    const float* tp = T + (size_t)(b*K + tid) * 16;
    #pragma unroll
    for (int c = 0; c < 12; ++c) t4[tid][c] = tp[c];
  }
  __syncthreads();

  const int kg    = tid & (KG - 1);
  const int slice = tid >> 5;

  float R[KPT][12];
  #pragma unroll
  for (int m = 0; m < KPT; ++m) {
    const int k = kg + m * KG;
    #pragma unroll
    for (int c = 0; c < 12; ++c) R[m][c] = t4[k][c];
  }

  float acc[KPT] = {0.f, 0.f, 0.f, 0.f};
  const int base = slice * PPS;
  #pragma unroll 4
  for (int i = 0; i < PPS; ++i) {
    const float4 p = sp[base + i];
    const float4 q = sq[base + i];
    #pragma unroll
    for (int m = 0; m < KPT; ++m) {
      const float dx = fmaf(R[m][0], p.x, fmaf(R[m][1], p.y, fmaf(R[m][2],  p.z, R[m][3])))  - q.x;
      const float dy = fmaf(R[m][4], p.x, fmaf(R[m][5], p.y, fmaf(R[m][6],  p.z, R[m][7])))  - q.y;
      const float dz = fmaf(R[m][8], p.x, fmaf(R[m][9], p.y, fmaf(R[m][10], p.z, R[m][11]))) - q.z;
      const float d2 = fmaf(dx, dx, fmaf(dy, dy, dz*dz));
      acc[m] = fmaf(p.w, fsqrt_(d2), acc[m]);
    }
  }

  #pragma unroll
  for (int m = 0; m < KPT; ++m)
    red[kg + m * KG][slice] = acc[m];
  __syncthreads();

  if (tid < K) {
    float sum = 0.f;
    #pragma unroll
    for (int s2 = 0; s2 < NSL; ++s2) sum += red[tid][s2];
    partial[((size_t)b * NCH + ch) * K + tid] = sum;
  }
}

// ---------------------------------------------------------------------------
// Kernel 3: argmin (byte-identical to R7)
// ---------------------------------------------------------------------------
__global__ __launch_bounds__(256) void argmin_kernel(
    const float* __restrict__ partial, const float* __restrict__ T,
    float* __restrict__ out)
{
  const int b   = blockIdx.x;
  const int tid = threadIdx.x;
  const int k   = tid & (K - 1);
  const int h   = tid >> 7;

  float sum = 0.f;
  #pragma unroll 7
  for (int c = h; c < NCH; c += 2)
    sum += partial[((size_t)b * NCH + c) * K + k];

  __shared__ float vals[256];
  __shared__ int   idxs[K];
  vals[tid] = sum;
  __syncthreads();

  if (tid < K) { vals[tid] = vals[tid] + vals[tid + K]; idxs[tid] = tid; }
  __syncthreads();

  for (int off = K / 2; off > 0; off >>= 1) {
    if (tid < off) {
      const float o = vals[tid + off];
      if (o < vals[tid] || (o == vals[tid] && idxs[tid + off] < idxs[tid])) {
        vals[tid] = o; idxs[tid] = idxs[tid + off];
      }
    }
    __syncthreads();
  }

  const int best = idxs[0];
  if (tid < 16) out[(size_t)b * 16 + tid] = T[(size_t)(b * K + best) * 16 + tid];
}

// ---------------------------------------------------------------------------
extern "C" void kernel_launch(void* const* d_in, const int* in_sizes, int n_in,
                              void* d_out, int out_size, void* d_ws, size_t ws_size,
                              hipStream_t stream) {
  const float* src = (const float*)d_in[0];
  const float* tgt = (const float*)d_in[1];
  const float* wts = (const float*)d_in[2];
  const int*   sel = (const int*)d_in[3];

  float* T       = (float*)d_ws;                 // B*K*16 floats
  float* partial = T + (size_t)B * K * 16;       // B*NCH*K floats

  gather_solve_kernel<<<B * K, 256, 0, stream>>>(src, tgt, wts, sel, T);
  error_kernel<<<B * NCH, 256, 0, stream>>>(src, tgt, wts, T, partial);
  argmin_kernel<<<B, 256, 0, stream>>>(partial, T, (float*)d_out);
}